// Round 1
// baseline (16.157 us; speedup 1.0000x reference)
//
#include <hip/hip_runtime.h>
#include <math.h>

#define NQ 9
#define QD 6
#define NBATCH 32

// RY on a register bit RB (literal): pairs (r, r|1<<RB)
#define RY_REG(C, SN, RB) do {                                   \
    _Pragma("unroll")                                            \
    for (int r = 0; r < 8; ++r) {                                \
      if (!(r & (1 << (RB)))) {                                  \
        const int r1_ = r | (1 << (RB));                         \
        const float a0_ = a[r], a1_ = a[r1_];                    \
        a[r]   = (C) * a0_ - (SN) * a1_;                         \
        a[r1_] = (SN) * a0_ + (C) * a1_;                         \
      }                                                          \
    }                                                            \
  } while (0)

// RY on a lane bit LB (literal after unroll): partner via shfl_xor
#define RY_LANE(C, SN, LB) do {                                  \
    const float sgn_ = ((lane >> (LB)) & 1) ? (SN) : -(SN);      \
    float p_[8];                                                 \
    _Pragma("unroll")                                            \
    for (int r = 0; r < 8; ++r)                                  \
      p_[r] = __shfl_xor(a[r], 1 << (LB), 64);                   \
    _Pragma("unroll")                                            \
    for (int r = 0; r < 8; ++r)                                  \
      a[r] = (C) * a[r] + sgn_ * p_[r];                          \
  } while (0)

// CNOT: ctrl lane bit CLB, target lane bit TLB
#define CNOT_LL(CLB, TLB) do {                                   \
    const bool ctl_ = (lane >> (CLB)) & 1;                       \
    float p_[8];                                                 \
    _Pragma("unroll")                                            \
    for (int r = 0; r < 8; ++r)                                  \
      p_[r] = __shfl_xor(a[r], 1 << (TLB), 64);                  \
    _Pragma("unroll")                                            \
    for (int r = 0; r < 8; ++r)                                  \
      a[r] = ctl_ ? p_[r] : a[r];                                \
  } while (0)

__global__ __launch_bounds__(64) void qst_kernel(
    const float* __restrict__ x,       // [32,54]
    const float* __restrict__ pre_w,   // [9,54]
    const float* __restrict__ pre_b,   // [9]
    const float* __restrict__ qp,      // [54] = [6,9]
    const float* __restrict__ post_w,  // [9,9]
    const float* __restrict__ post_b,  // [9]
    float* __restrict__ out)           // [32,9]
{
  const int b = blockIdx.x;
  const int lane = (int)threadIdx.x;  // 0..63, one wave per batch element

  // state: idx = lane*8 + r. lane bits = idx bits 3..8, reg bits = idx bits 0..2.
  // wire w -> idx bit (8-w): w=0..5 -> lane bit (5-w); w=6,7,8 -> reg bit 2,1,0.
  float a[8];
  #pragma unroll
  for (int r = 0; r < 8; ++r) a[r] = 0.044194173824159216f;  // 1/sqrt(512)

  const float xv = (lane < 54) ? x[b * 54 + lane] : 0.0f;

  // ---- input RY layer: theta_w = tanh(x.pre_w[w] + pre_b[w]) * pi/2 ----
  #pragma unroll
  for (int w = 0; w < NQ; ++w) {
    const float pw = (lane < 54) ? pre_w[w * 54 + lane] : 0.0f;
    float s = xv * pw;
    #pragma unroll
    for (int off = 32; off >= 1; off >>= 1) s += __shfl_xor(s, off, 64);
    const float h = tanhf(s + pre_b[w]) * 0.78539816339744831f;  // theta/2
    const float c = __cosf(h), sn = __sinf(h);
    if (w < 6)      { RY_LANE(c, sn, 5 - w); }
    else if (w == 6) RY_REG(c, sn, 2);
    else if (w == 7) RY_REG(c, sn, 1);
    else             RY_REG(c, sn, 0);
  }

  // ---- 6 depth iterations ----
  for (int k = 0; k < QD; ++k) {
    // even CNOT layer: wires (0,1),(2,3),(4,5),(6,7)
    CNOT_LL(5, 4);  // (0,1): ctrl lane b5, tgt lane b4
    CNOT_LL(3, 2);  // (2,3)
    CNOT_LL(1, 0);  // (4,5)
    // (6,7): ctrl reg b2, tgt reg b1 -> swap (4,6),(5,7)
    { float t = a[4]; a[4] = a[6]; a[6] = t;
      t = a[5]; a[5] = a[7]; a[7] = t; }

    // odd CNOT layer: wires (1,2),(3,4),(5,6),(7,8)
    CNOT_LL(4, 3);  // (1,2)
    CNOT_LL(2, 1);  // (3,4)
    // (5,6): ctrl lane b0, tgt reg b2 -> cond-swap (r, r+4)
    { const bool ctl = lane & 1;
      #pragma unroll
      for (int r = 0; r < 4; ++r) {
        const float lo = a[r], hi = a[r + 4];
        a[r]     = ctl ? hi : lo;
        a[r + 4] = ctl ? lo : hi;
      } }
    // (7,8): ctrl reg b1, tgt reg b0 -> swap (2,3),(6,7)
    { float t = a[2]; a[2] = a[3]; a[3] = t;
      t = a[6]; a[6] = a[7]; a[7] = t; }

    // weight RY layer: theta = q_params[k,w], half = *0.5
    #pragma unroll
    for (int w = 0; w < 6; ++w) {
      const float h = qp[k * NQ + w] * 0.5f;
      const float c = __cosf(h), sn = __sinf(h);
      RY_LANE(c, sn, 5 - w);
    }
    { const float h = qp[k * NQ + 6] * 0.5f; const float c = __cosf(h), sn = __sinf(h); RY_REG(c, sn, 2); }
    { const float h = qp[k * NQ + 7] * 0.5f; const float c = __cosf(h), sn = __sinf(h); RY_REG(c, sn, 1); }
    { const float h = qp[k * NQ + 8] * 0.5f; const float c = __cosf(h), sn = __sinf(h); RY_REG(c, sn, 0); }
  }

  // ---- expectations <Z_w> ----
  float sq[8];
  #pragma unroll
  for (int r = 0; r < 8; ++r) sq[r] = a[r] * a[r];
  const float S  = ((sq[0] + sq[1]) + (sq[2] + sq[3])) + ((sq[4] + sq[5]) + (sq[6] + sq[7]));
  const float T2 = ((sq[0] + sq[1]) + (sq[2] + sq[3])) - ((sq[4] + sq[5]) + (sq[6] + sq[7]));
  const float T1 = ((sq[0] + sq[1]) + (sq[4] + sq[5])) - ((sq[2] + sq[3]) + (sq[6] + sq[7]));
  const float T0 = ((sq[0] + sq[2]) + (sq[4] + sq[6])) - ((sq[1] + sq[3]) + (sq[5] + sq[7]));

  float q[9];
  #pragma unroll
  for (int w = 0; w < 6; ++w)
    q[w] = ((lane >> (5 - w)) & 1) ? -S : S;
  q[6] = T2; q[7] = T1; q[8] = T0;

  #pragma unroll
  for (int w = 0; w < NQ; ++w) {
    #pragma unroll
    for (int off = 32; off >= 1; off >>= 1)
      q[w] += __shfl_xor(q[w], off, 64);
  }

  // ---- post layer ----
  if (lane < NQ) {
    float acc = post_b[lane];
    #pragma unroll
    for (int w = 0; w < NQ; ++w) acc += q[w] * post_w[lane * NQ + w];
    out[b * NQ + lane] = acc;
  }
}

extern "C" void kernel_launch(void* const* d_in, const int* in_sizes, int n_in,
                              void* d_out, int out_size, void* d_ws, size_t ws_size,
                              hipStream_t stream) {
  qst_kernel<<<NBATCH, 64, 0, stream>>>(
      (const float*)d_in[0], (const float*)d_in[1], (const float*)d_in[2],
      (const float*)d_in[3], (const float*)d_in[4], (const float*)d_in[5],
      (float*)d_out);
}

// Round 2
// 11.461 us; speedup vs baseline: 1.4098x; 1.4098x over previous
//
#include <hip/hip_runtime.h>
#include <math.h>

#define NQ 9
#define QD 6
#define NBATCH 32

__device__ __forceinline__ float bperm_f(int srcLane, float v) {
  return __int_as_float(__builtin_amdgcn_ds_bpermute(srcLane << 2, __float_as_int(v)));
}
__device__ __forceinline__ float rdlane_f(float v, int l) {
  return __int_as_float(__builtin_amdgcn_readlane(__float_as_int(v), l));
}
__device__ __forceinline__ float tanh_fast(float x) {
  const float e = __expf(2.0f * x);   // overflow->inf->tanh=1, underflow->0->tanh=-1: exact limits
  return 1.0f - 2.0f / (e + 1.0f);
}

// RY on a register bit RB (literal): pairs (r, r|1<<RB)
#define RY_REG(C, SN, RB) do {                                   \
    _Pragma("unroll")                                            \
    for (int r = 0; r < 8; ++r) {                                \
      if (!(r & (1 << (RB)))) {                                  \
        const int r1_ = r | (1 << (RB));                         \
        const float a0_ = a[r], a1_ = a[r1_];                    \
        a[r]   = (C) * a0_ - (SN) * a1_;                         \
        a[r1_] = (SN) * a0_ + (C) * a1_;                         \
      }                                                          \
    }                                                            \
  } while (0)

// RY on a lane bit LB (literal after unroll): partner via shfl_xor
#define RY_LANE(C, SN, LB) do {                                  \
    const float sgn_ = ((lane >> (LB)) & 1) ? (SN) : -(SN);      \
    float p_[8];                                                 \
    _Pragma("unroll")                                            \
    for (int r = 0; r < 8; ++r)                                  \
      p_[r] = __shfl_xor(a[r], 1 << (LB), 64);                   \
    _Pragma("unroll")                                            \
    for (int r = 0; r < 8; ++r)                                  \
      a[r] = (C) * a[r] + sgn_ * p_[r];                          \
  } while (0)

__global__ __launch_bounds__(64) void qst_kernel(
    const float* __restrict__ x,       // [32,54]
    const float* __restrict__ pre_w,   // [9,54]
    const float* __restrict__ pre_b,   // [9]
    const float* __restrict__ qp,      // [54] = [6,9]
    const float* __restrict__ post_w,  // [9,9]
    const float* __restrict__ post_b,  // [9]
    float* __restrict__ out)           // [32,9]
{
  const int b = blockIdx.x;
  const int lane = (int)threadIdx.x;  // 0..63, one wave per batch element

  // ---- circuit-weight trig, lane-parallel: lane i holds cos/sin(qp[i]/2) ----
  const float qv = (lane < 54) ? qp[lane] : 0.0f;
  const float qc = __cosf(qv * 0.5f);
  const float qs = __sinf(qv * 0.5f);

  // ---- pre-layer: 9 interleaved 64-lane reductions ----
  const float xv = (lane < 54) ? x[b * 54 + lane] : 0.0f;
  float s9[NQ];
  #pragma unroll
  for (int w = 0; w < NQ; ++w) {
    const float pw = (lane < 54) ? pre_w[w * 54 + lane] : 0.0f;
    s9[w] = xv * pw;
  }
  #pragma unroll
  for (int st = 0; st < 6; ++st) {
    #pragma unroll
    for (int w = 0; w < NQ; ++w) s9[w] += __shfl_xor(s9[w], 1 << st, 64);
  }
  float ic[NQ], is[NQ];
  #pragma unroll
  for (int w = 0; w < NQ; ++w) {
    const float h = tanh_fast(s9[w] + pre_b[w]) * 0.78539816339744831f;  // theta/2
    ic[w] = __cosf(h);
    is[w] = __sinf(h);
  }

  // state: idx = lane*8 + r. lane bits 5..0 = idx bits 8..3, reg bits = idx bits 2..0.
  // wire w -> idx bit (8-w): w=0..5 -> lane bit (5-w); w=6,7,8 -> reg bit 2,1,0.
  float a[8];
  #pragma unroll
  for (int r = 0; r < 8; ++r) a[r] = 0.044194173824159216f;  // 1/sqrt(512)

  // ---- input RY layer ----
  #pragma unroll
  for (int w = 0; w < 6; ++w) RY_LANE(ic[w], is[w], 5 - w);
  RY_REG(ic[6], is[6], 2);
  RY_REG(ic[7], is[7], 1);
  RY_REG(ic[8], is[8], 0);

  // ---- 6 depth iterations ----
  // Both CNOT layers fused: gather map T(i): out[i] = in[T(i)], T linear over GF(2):
  //  srcLane = lane ^ ((lane>>1)&0x1F) ^ ((lane>>2)&0x05)   (same for all regs)
  //  srcReg  = s0(r) ^ (lane&1 ? 6 : 0), s0 = [0,1,3,2,6,7,5,4]
  #pragma unroll
  for (int k = 0; k < QD; ++k) {
    const int srcLane = lane ^ ((lane >> 1) & 0x1F) ^ ((lane >> 2) & 0x05);
    float u[8];
    #pragma unroll
    for (int r = 0; r < 8; ++r) u[r] = bperm_f(srcLane, a[r]);
    const bool L0 = lane & 1;
    a[0] = L0 ? u[6] : u[0];
    a[1] = L0 ? u[7] : u[1];
    a[2] = L0 ? u[5] : u[3];
    a[3] = L0 ? u[4] : u[2];
    a[4] = L0 ? u[0] : u[6];
    a[5] = L0 ? u[1] : u[7];
    a[6] = L0 ? u[3] : u[5];
    a[7] = L0 ? u[2] : u[4];

    // weight RY layer: broadcast cos/sin from lane k*9+w
    #pragma unroll
    for (int w = 0; w < 6; ++w) {
      const float c  = rdlane_f(qc, k * NQ + w);
      const float sn = rdlane_f(qs, k * NQ + w);
      RY_LANE(c, sn, 5 - w);
    }
    { const float c = rdlane_f(qc, k * NQ + 6), sn = rdlane_f(qs, k * NQ + 6); RY_REG(c, sn, 2); }
    { const float c = rdlane_f(qc, k * NQ + 7), sn = rdlane_f(qs, k * NQ + 7); RY_REG(c, sn, 1); }
    { const float c = rdlane_f(qc, k * NQ + 8), sn = rdlane_f(qs, k * NQ + 8); RY_REG(c, sn, 0); }
  }

  // ---- expectations <Z_w> ----
  float sq[8];
  #pragma unroll
  for (int r = 0; r < 8; ++r) sq[r] = a[r] * a[r];
  const float S  = ((sq[0] + sq[1]) + (sq[2] + sq[3])) + ((sq[4] + sq[5]) + (sq[6] + sq[7]));
  const float T2 = ((sq[0] + sq[1]) + (sq[2] + sq[3])) - ((sq[4] + sq[5]) + (sq[6] + sq[7]));
  const float T1 = ((sq[0] + sq[1]) + (sq[4] + sq[5])) - ((sq[2] + sq[3]) + (sq[6] + sq[7]));
  const float T0 = ((sq[0] + sq[2]) + (sq[4] + sq[6])) - ((sq[1] + sq[3]) + (sq[5] + sq[7]));

  float q[NQ];
  #pragma unroll
  for (int w = 0; w < 6; ++w)
    q[w] = ((lane >> (5 - w)) & 1) ? -S : S;
  q[6] = T2; q[7] = T1; q[8] = T0;

  #pragma unroll
  for (int w = 0; w < NQ; ++w) {
    #pragma unroll
    for (int off = 32; off >= 1; off >>= 1)
      q[w] += __shfl_xor(q[w], off, 64);
  }

  // ---- post layer ----
  if (lane < NQ) {
    float acc = post_b[lane];
    #pragma unroll
    for (int w = 0; w < NQ; ++w) acc += q[w] * post_w[lane * NQ + w];
    out[b * NQ + lane] = acc;
  }
}

extern "C" void kernel_launch(void* const* d_in, const int* in_sizes, int n_in,
                              void* d_out, int out_size, void* d_ws, size_t ws_size,
                              hipStream_t stream) {
  qst_kernel<<<NBATCH, 64, 0, stream>>>(
      (const float*)d_in[0], (const float*)d_in[1], (const float*)d_in[2],
      (const float*)d_in[3], (const float*)d_in[4], (const float*)d_in[5],
      (float*)d_out);
}

// Round 4
// 10.727 us; speedup vs baseline: 1.5062x; 1.0684x over previous
//
#include <hip/hip_runtime.h>
#include <math.h>

#define NQ 9
#define QD 6
#define NBATCH 32

typedef int v2i __attribute__((ext_vector_type(2)));

__device__ __forceinline__ int   f2i(float x) { return __float_as_int(x); }
__device__ __forceinline__ float i2f(int x)   { return __int_as_float(x); }

__device__ __forceinline__ float bperm_f(int srcLane, float v) {
  return i2f(__builtin_amdgcn_ds_bpermute(srcLane << 2, f2i(v)));
}
__device__ __forceinline__ float rdlane_f(float v, int l) {
  return i2f(__builtin_amdgcn_readlane(f2i(v), l));
}
__device__ __forceinline__ float tanh_fast(float x) {
  const float e = __expf(2.0f * x);   // limits exact: inf->1, 0->-1
  return 1.0f - 2.0f / (e + 1.0f);
}

// cross-lane xor-by-MASK on the cheapest pipe for that mask
template <int MASK>
__device__ __forceinline__ float shx(float v, int lane) {
  if constexpr (MASK == 1) {        // quad_perm [1,0,3,2] — VALU DPP
    return i2f(__builtin_amdgcn_mov_dpp(f2i(v), 0xB1, 0xF, 0xF, true));
  } else if constexpr (MASK == 2) { // quad_perm [2,3,0,1] — VALU DPP
    return i2f(__builtin_amdgcn_mov_dpp(f2i(v), 0x4E, 0xF, 0xF, true));
  } else if constexpr (MASK == 4) {
    return i2f(__builtin_amdgcn_ds_swizzle(f2i(v), 0x101F));
  } else if constexpr (MASK == 8) {
    return i2f(__builtin_amdgcn_ds_swizzle(f2i(v), 0x201F));
  } else if constexpr (MASK == 16) {
    return i2f(__builtin_amdgcn_ds_swizzle(f2i(v), 0x401F));
  } else {                          // MASK == 32 — VALU permlane
#if __has_builtin(__builtin_amdgcn_permlane32_swap)
    // r.x = low half of v replicated into both halves; r.y = high half.
    // xor-32 partner: lane<32 wants the HIGH half (r.y); lane>=32 wants LOW (r.x).
    v2i r = __builtin_amdgcn_permlane32_swap(f2i(v), f2i(v), false, false);
    return i2f((lane & 32) ? r.x : r.y);
#else
    return __shfl_xor(v, 32, 64);
#endif
  }
}

// RY on a lane bit (MASK = 1<<bit)
template <int MASK>
__device__ __forceinline__ void ry_lane(float (&a)[8], float c, float s, int lane) {
  const float sgn = (lane & MASK) ? s : -s;
  float p[8];
  #pragma unroll
  for (int r = 0; r < 8; ++r) p[r] = shx<MASK>(a[r], lane);
  #pragma unroll
  for (int r = 0; r < 8; ++r) a[r] = c * a[r] + sgn * p[r];
}

// RY on a register bit RB
template <int RB>
__device__ __forceinline__ void ry_reg(float (&a)[8], float c, float s) {
  #pragma unroll
  for (int r = 0; r < 8; ++r) {
    if (!(r & (1 << RB))) {
      const int r1 = r | (1 << RB);
      const float a0 = a[r], a1 = a[r1];
      a[r]  = c * a0 - s * a1;
      a[r1] = s * a0 + c * a1;
    }
  }
}

// full 64-lane butterfly sum of N interleaved values
template <int N>
__device__ __forceinline__ void red64(float (&v)[N], int lane) {
  #pragma unroll
  for (int w = 0; w < N; ++w) v[w] += shx<1>(v[w], lane);
  #pragma unroll
  for (int w = 0; w < N; ++w) v[w] += shx<2>(v[w], lane);
  #pragma unroll
  for (int w = 0; w < N; ++w) v[w] += shx<4>(v[w], lane);
  #pragma unroll
  for (int w = 0; w < N; ++w) v[w] += shx<8>(v[w], lane);
  #pragma unroll
  for (int w = 0; w < N; ++w) v[w] += shx<16>(v[w], lane);
  #pragma unroll
  for (int w = 0; w < N; ++w) v[w] += shx<32>(v[w], lane);
}

__global__ __launch_bounds__(64) void qst_kernel(
    const float* __restrict__ x,       // [32,54]
    const float* __restrict__ pre_w,   // [9,54]
    const float* __restrict__ pre_b,   // [9]
    const float* __restrict__ qp,      // [54] = [6,9]
    const float* __restrict__ post_w,  // [9,9]
    const float* __restrict__ post_b,  // [9]
    float* __restrict__ out)           // [32,9]
{
  const int b = blockIdx.x;
  const int lane = (int)threadIdx.x;  // one wave per batch element

  // ---- circuit-weight trig, lane-parallel: lane i holds cos/sin(qp[i]/2) ----
  const float qv = (lane < 54) ? qp[lane] : 0.0f;
  const float qc = __cosf(qv * 0.5f);
  const float qs = __sinf(qv * 0.5f);

  // ---- pre-layer: 9 interleaved 64-lane reductions ----
  const float xv = (lane < 54) ? x[b * 54 + lane] : 0.0f;
  float s9[NQ];
  #pragma unroll
  for (int w = 0; w < NQ; ++w) {
    const float pw = (lane < 54) ? pre_w[w * 54 + lane] : 0.0f;
    s9[w] = xv * pw;
  }
  red64<NQ>(s9, lane);
  float ic[NQ], is[NQ];
  #pragma unroll
  for (int w = 0; w < NQ; ++w) {
    const float h = tanh_fast(s9[w] + pre_b[w]) * 0.78539816339744831f;  // theta/2
    ic[w] = __cosf(h);
    is[w] = __sinf(h);
  }

  // state: idx = lane*8 + r. lane bits 5..0 = idx bits 8..3, reg bits = idx bits 2..0.
  // wire w -> idx bit (8-w): w=0..5 -> lane bit (5-w) -> MASK 1<<(5-w); w=6,7,8 -> reg bit 2,1,0.
  float a[8];
  #pragma unroll
  for (int r = 0; r < 8; ++r) a[r] = 0.044194173824159216f;  // 1/sqrt(512)

  // ---- input RY layer ----
  ry_lane<32>(a, ic[0], is[0], lane);
  ry_lane<16>(a, ic[1], is[1], lane);
  ry_lane< 8>(a, ic[2], is[2], lane);
  ry_lane< 4>(a, ic[3], is[3], lane);
  ry_lane< 2>(a, ic[4], is[4], lane);
  ry_lane< 1>(a, ic[5], is[5], lane);
  ry_reg<2>(a, ic[6], is[6]);
  ry_reg<1>(a, ic[7], is[7]);
  ry_reg<0>(a, ic[8], is[8]);

  // ---- 6 depth iterations ----
  // Both CNOT layers fused into one gather: out[i] = in[T(i)], T linear over GF(2):
  //  srcLane = lane ^ ((lane>>1)&0x1F) ^ ((lane>>2)&0x05)   (same for all regs)
  //  srcReg  = s0(r) ^ (lane&1 ? 6 : 0), s0 = [0,1,3,2,6,7,5,4]
  const int srcLane = lane ^ ((lane >> 1) & 0x1F) ^ ((lane >> 2) & 0x05);
  #pragma unroll
  for (int k = 0; k < QD; ++k) {
    float u[8];
    #pragma unroll
    for (int r = 0; r < 8; ++r) u[r] = bperm_f(srcLane, a[r]);
    const bool L0 = lane & 1;
    a[0] = L0 ? u[6] : u[0];
    a[1] = L0 ? u[7] : u[1];
    a[2] = L0 ? u[5] : u[3];
    a[3] = L0 ? u[4] : u[2];
    a[4] = L0 ? u[0] : u[6];
    a[5] = L0 ? u[1] : u[7];
    a[6] = L0 ? u[3] : u[5];
    a[7] = L0 ? u[2] : u[4];

    // weight RY layer: broadcast cos/sin from lane k*9+w
    ry_lane<32>(a, rdlane_f(qc, k * NQ + 0), rdlane_f(qs, k * NQ + 0), lane);
    ry_lane<16>(a, rdlane_f(qc, k * NQ + 1), rdlane_f(qs, k * NQ + 1), lane);
    ry_lane< 8>(a, rdlane_f(qc, k * NQ + 2), rdlane_f(qs, k * NQ + 2), lane);
    ry_lane< 4>(a, rdlane_f(qc, k * NQ + 3), rdlane_f(qs, k * NQ + 3), lane);
    ry_lane< 2>(a, rdlane_f(qc, k * NQ + 4), rdlane_f(qs, k * NQ + 4), lane);
    ry_lane< 1>(a, rdlane_f(qc, k * NQ + 5), rdlane_f(qs, k * NQ + 5), lane);
    ry_reg<2>(a, rdlane_f(qc, k * NQ + 6), rdlane_f(qs, k * NQ + 6));
    ry_reg<1>(a, rdlane_f(qc, k * NQ + 7), rdlane_f(qs, k * NQ + 7));
    ry_reg<0>(a, rdlane_f(qc, k * NQ + 8), rdlane_f(qs, k * NQ + 8));
  }

  // ---- expectations <Z_w> ----
  float sq[8];
  #pragma unroll
  for (int r = 0; r < 8; ++r) sq[r] = a[r] * a[r];
  const float S  = ((sq[0] + sq[1]) + (sq[2] + sq[3])) + ((sq[4] + sq[5]) + (sq[6] + sq[7]));
  const float T2 = ((sq[0] + sq[1]) + (sq[2] + sq[3])) - ((sq[4] + sq[5]) + (sq[6] + sq[7]));
  const float T1 = ((sq[0] + sq[1]) + (sq[4] + sq[5])) - ((sq[2] + sq[3]) + (sq[6] + sq[7]));
  const float T0 = ((sq[0] + sq[2]) + (sq[4] + sq[6])) - ((sq[1] + sq[3]) + (sq[5] + sq[7]));

  float q[NQ];
  #pragma unroll
  for (int w = 0; w < 6; ++w)
    q[w] = ((lane >> (5 - w)) & 1) ? -S : S;
  q[6] = T2; q[7] = T1; q[8] = T0;

  red64<NQ>(q, lane);

  // ---- post layer ----
  if (lane < NQ) {
    float acc = post_b[lane];
    #pragma unroll
    for (int w = 0; w < NQ; ++w) acc += q[w] * post_w[lane * NQ + w];
    out[b * NQ + lane] = acc;
  }
}

extern "C" void kernel_launch(void* const* d_in, const int* in_sizes, int n_in,
                              void* d_out, int out_size, void* d_ws, size_t ws_size,
                              hipStream_t stream) {
  qst_kernel<<<NBATCH, 64, 0, stream>>>(
      (const float*)d_in[0], (const float*)d_in[1], (const float*)d_in[2],
      (const float*)d_in[3], (const float*)d_in[4], (const float*)d_in[5],
      (float*)d_out);
}